// Round 1
// baseline (11498.772 us; speedup 1.0000x reference)
//
#include <hip/hip_runtime.h>
#include <cstddef>

// Model dims
#define HD    768
#define ID    1536
#define ND    16
#define KD    4
#define RD    48
#define NLAY  8
#define BB    4
#define LL    1024
#define BL    4096   // BB*LL
#define DIN   13
#define DA_   128
#define RP_   4

// ---------------- Generic tiled fp32 GEMM: C = act(A @ W^T + bias) (+res) ----
// A: (M,K) row-major with stride lda; W: (N,K) row-major stride K;
// act: 0=none 1=relu 2=tanh 3=softplus
#define BM 64
#define BN 64
#define BKK 16

__device__ __forceinline__ float softplus_f(float x) {
    return (x > 20.f) ? x : log1pf(expf(x));
}

__global__ __launch_bounds__(256) void gemm_k(
    const float* __restrict__ A, int lda,
    const float* __restrict__ W,
    const float* __restrict__ bias,
    const float* __restrict__ res, int ldres,
    float* __restrict__ C, int ldc,
    int M, int N, int K, int act)
{
    __shared__ float As[BKK][BM + 4];
    __shared__ float Ws[BKK][BN + 4];
    int tid = threadIdx.x;
    int tx = tid & 15, ty = tid >> 4;
    int m0 = blockIdx.y * BM, n0 = blockIdx.x * BN;
    float acc[4][4] = {};

    int arow = tid >> 2;          // 0..63
    int acol = (tid & 3) * 4;     // 0,4,8,12

    for (int k0 = 0; k0 < K; k0 += BKK) {
        int gm = m0 + arow;
        int gn = n0 + arow;
#pragma unroll
        for (int j = 0; j < 4; ++j) {
            int gk = k0 + acol + j;
            float av = 0.f, wv = 0.f;
            if (gm < M && gk < K) av = A[(size_t)gm * lda + gk];
            if (gn < N && gk < K) wv = W[(size_t)gn * K + gk];
            As[acol + j][arow] = av;
            Ws[acol + j][arow] = wv;
        }
        __syncthreads();
#pragma unroll
        for (int k = 0; k < BKK; ++k) {
            float a[4], b[4];
#pragma unroll
            for (int i = 0; i < 4; ++i) a[i] = As[k][ty * 4 + i];
#pragma unroll
            for (int j = 0; j < 4; ++j) b[j] = Ws[k][tx * 4 + j];
#pragma unroll
            for (int i = 0; i < 4; ++i)
#pragma unroll
                for (int j = 0; j < 4; ++j)
                    acc[i][j] += a[i] * b[j];
        }
        __syncthreads();
    }

#pragma unroll
    for (int i = 0; i < 4; ++i) {
        int row = m0 + ty * 4 + i;
        if (row >= M) continue;
#pragma unroll
        for (int j = 0; j < 4; ++j) {
            int col = n0 + tx * 4 + j;
            if (col >= N) continue;
            float v = acc[i][j];
            if (bias) v += bias[col];
            if (act == 1) v = fmaxf(v, 0.f);
            else if (act == 2) v = tanhf(v);
            else if (act == 3) v = softplus_f(v);
            if (res) v += res[(size_t)row * ldres + col];
            C[(size_t)row * ldc + col] = v;
        }
    }
}

// ---------------- RMSNorm over 768 ----------------
__global__ __launch_bounds__(256) void rmsnorm_k(
    const float* __restrict__ x, const float* __restrict__ w,
    float* __restrict__ out)
{
    int row = blockIdx.x;
    const float* xr = x + (size_t)row * HD;
    int tid = threadIdx.x;
    float v0 = xr[tid], v1 = xr[tid + 256], v2 = xr[tid + 512];
    __shared__ float red[256];
    red[tid] = v0 * v0 + v1 * v1 + v2 * v2;
    __syncthreads();
    for (int o = 128; o; o >>= 1) {
        if (tid < o) red[tid] += red[tid + o];
        __syncthreads();
    }
    float scale = rsqrtf(red[0] / (float)HD + 1e-5f);
    float* outr = out + (size_t)row * HD;
    outr[tid]       = v0 * scale * w[tid];
    outr[tid + 256] = v1 * scale * w[tid + 256];
    outr[tid + 512] = v2 * scale * w[tid + 512];
}

// ---------------- Causal depthwise conv (K=4) + bias + SiLU ----------------
// proj (BL,3072), take first ID cols as hs; u[b,t,i] out (BL,ID)
__global__ __launch_bounds__(256) void conv_silu_k(
    const float* __restrict__ proj, const float* __restrict__ cw,
    const float* __restrict__ cb, float* __restrict__ u)
{
    size_t idx = (size_t)blockIdx.x * 256 + threadIdx.x;
    if (idx >= (size_t)BL * ID) return;
    int i = (int)(idx % ID);
    int t = (int)((idx / ID) % LL);
    int b = (int)(idx / ((size_t)ID * LL));
    float s = cb[i];
#pragma unroll
    for (int k = 0; k < KD; ++k) {
        int tt = t - (KD - 1) + k;
        if (tt >= 0)
            s += proj[((size_t)(b * LL + tt)) * (2 * ID) + i] * cw[i * KD + k];
    }
    u[idx] = s / (1.f + expf(-s));
}

// ---------------- Selective scan ----------------
// lane layout: n = tid&15, il = tid>>4 ; block handles one b, 16 i's
__global__ __launch_bounds__(256) void scan_k(
    const float* __restrict__ dt,    // (BL,ID)
    const float* __restrict__ ssm,   // (BL,80): B at +48, C at +64
    const float* __restrict__ u,     // (BL,ID)
    const float* __restrict__ proj,  // (BL,2*ID): gate at +ID
    const float* __restrict__ A_log, // (ID,ND) this layer
    const float* __restrict__ D,     // (ID)
    float* __restrict__ y)           // (BL,ID)
{
    int b = blockIdx.y;
    int iBase = blockIdx.x * 16;
    int tid = threadIdx.x;
    int n = tid & 15, il = tid >> 4;
    int i = iBase + il;
    float Ain = -expf(A_log[i * ND + n]);
    float Dv = D[i];
    float h = 0.f;
    __shared__ float sdt[64][16], su[64][16], sg[64][16], sB[64][16], sC[64][16];

    for (int t0 = 0; t0 < LL; t0 += 64) {
        __syncthreads();
#pragma unroll
        for (int rr = 0; rr < 4; ++rr) {
            int tt = (tid >> 4) + rr * 16;
            int ii = tid & 15;
            size_t row = (size_t)(b * LL + t0 + tt);
            sdt[tt][ii] = dt[row * ID + iBase + ii];
            su[tt][ii]  = u[row * ID + iBase + ii];
            sg[tt][ii]  = proj[row * (2 * ID) + ID + iBase + ii];
            sB[tt][ii]  = ssm[row * 80 + 48 + ii];
            sC[tt][ii]  = ssm[row * 80 + 64 + ii];
        }
        __syncthreads();
        for (int tt = 0; tt < 64; ++tt) {
            float dtv = sdt[tt][il];
            float uv  = su[tt][il];
            float bv  = sB[tt][n];
            float cv  = sC[tt][n];
            float dA = expf(dtv * Ain);
            h = dA * h + dtv * uv * bv;
            float p = h * cv;
            p += __shfl_xor(p, 1);
            p += __shfl_xor(p, 2);
            p += __shfl_xor(p, 4);
            p += __shfl_xor(p, 8);
            if (n == 0) {
                float g = sg[tt][il];
                float yv = (p + uv * Dv) * (g / (1.f + expf(-g)));
                y[(size_t)(b * LL + t0 + tt) * ID + i] = yv;
            }
        }
    }
}

// ---------------- Softmax over L per (b,r) ----------------
__global__ __launch_bounds__(256) void softmax_k(
    const float* __restrict__ s, float* __restrict__ attn)
{
    int b = blockIdx.x >> 2, r = blockIdx.x & 3;
    int tid = threadIdx.x;
    __shared__ float red[256];
    float mx = -1e30f;
    for (int j = 0; j < 4; ++j) {
        int t = tid + j * 256;
        mx = fmaxf(mx, s[((size_t)(b * LL + t)) * RP_ + r]);
    }
    red[tid] = mx;
    __syncthreads();
    for (int o = 128; o; o >>= 1) {
        if (tid < o) red[tid] = fmaxf(red[tid], red[tid + o]);
        __syncthreads();
    }
    mx = red[0];
    __syncthreads();
    float ev[4], sum = 0.f;
    for (int j = 0; j < 4; ++j) {
        int t = tid + j * 256;
        ev[j] = expf(s[((size_t)(b * LL + t)) * RP_ + r] - mx);
        sum += ev[j];
    }
    red[tid] = sum;
    __syncthreads();
    for (int o = 128; o; o >>= 1) {
        if (tid < o) red[tid] += red[tid + o];
        __syncthreads();
    }
    float inv = 1.f / red[0];
    for (int j = 0; j < 4; ++j) {
        int t = tid + j * 256;
        attn[((size_t)(b * LL + t)) * RP_ + r] = ev[j] * inv;
    }
}

// ---------------- attn pool: m[b,r,h] = sum_t attn[b,t,r]*hn[b,t,h] ---------
__global__ __launch_bounds__(256) void pool_k(
    const float* __restrict__ attn, const float* __restrict__ hn,
    float* __restrict__ m)
{
    int b = blockIdx.x >> 2, r = blockIdx.x & 3;
    int tid = threadIdx.x;
    float acc0 = 0.f, acc1 = 0.f, acc2 = 0.f;
    for (int t = 0; t < LL; ++t) {
        float w = attn[((size_t)(b * LL + t)) * RP_ + r];
        const float* hr = hn + ((size_t)(b * LL + t)) * HD;
        acc0 += w * hr[tid];
        acc1 += w * hr[tid + 256];
        acc2 += w * hr[tid + 512];
    }
    float* out = m + ((size_t)(b * RP_ + r)) * HD;
    out[tid] = acc0;
    out[tid + 256] = acc1;
    out[tid + 512] = acc2;
}

// ---------------- small-M GEMV: C[b,n] = act(dot(A[b,:],W[n,:]) + bias) -----
__global__ __launch_bounds__(64) void gemv_k(
    const float* __restrict__ A, int lda,
    const float* __restrict__ W, const float* __restrict__ bias,
    float* __restrict__ C, int ldc, int K, int relu)
{
    int n = blockIdx.x, b = blockIdx.y;
    int lane = threadIdx.x;
    const float* a = A + (size_t)b * lda;
    const float* w = W + (size_t)n * K;
    float s = 0.f;
    for (int k = lane; k < K; k += 64) s += a[k] * w[k];
    for (int off = 32; off; off >>= 1) s += __shfl_down(s, off);
    if (lane == 0) {
        float v = s + (bias ? bias[n] : 0.f);
        if (relu) v = fmaxf(v, 0.f);
        C[(size_t)b * ldc + n] = v;
    }
}

extern "C" void kernel_launch(void* const* d_in, const int* in_sizes, int n_in,
                              void* d_out, int out_size, void* d_ws, size_t ws_size,
                              hipStream_t stream) {
    const float* x          = (const float*)d_in[0];
    const float* mlp_in_w1  = (const float*)d_in[1];
    const float* mlp_in_b1  = (const float*)d_in[2];
    const float* mlp_in_w2  = (const float*)d_in[3];
    const float* mlp_in_b2  = (const float*)d_in[4];
    const float* mlp_in_w3  = (const float*)d_in[5];
    const float* mlp_in_b3  = (const float*)d_in[6];
    const float* norm_w     = (const float*)d_in[7];   // (NL,H)
    const float* in_proj_w  = (const float*)d_in[8];   // (NL,2I,H)
    const float* conv_w     = (const float*)d_in[9];   // (NL,I,K)
    const float* conv_b     = (const float*)d_in[10];  // (NL,I)
    const float* x_proj_w   = (const float*)d_in[11];  // (NL,80,I)
    const float* dt_w       = (const float*)d_in[12];  // (NL,I,R)
    const float* dt_b       = (const float*)d_in[13];  // (NL,I)
    const float* A_log      = (const float*)d_in[14];  // (NL,I,N)
    const float* Dp         = (const float*)d_in[15];  // (NL,I)
    const float* out_proj_w = (const float*)d_in[16];  // (NL,H,I)
    const float* norm_f_w   = (const float*)d_in[17];
    const float* attn_ws1   = (const float*)d_in[18];  // (DA,H)
    const float* attn_ws2   = (const float*)d_in[19];  // (RP,DA)
    const float* mlp_out_w1 = (const float*)d_in[20];  // (256, 3072)
    const float* mlp_out_b1 = (const float*)d_in[21];
    const float* mlp_out_w2 = (const float*)d_in[22];
    const float* mlp_out_b2 = (const float*)d_in[23];
    const float* mlp_out_w3 = (const float*)d_in[24];  // (1,256)
    const float* mlp_out_b3 = (const float*)d_in[25];
    float* out = (float*)d_out;

    float* ws   = (float*)d_ws;
    float* h    = ws;                       // BL*HD
    float* hn   = h    + (size_t)BL * HD;   // BL*HD
    float* proj = hn   + (size_t)BL * HD;   // BL*2I
    float* u    = proj + (size_t)BL * 2 * ID; // BL*I
    float* dtb  = u    + (size_t)BL * ID;   // BL*I
    float* yb   = dtb  + (size_t)BL * ID;   // BL*I
    float* ssm  = yb   + (size_t)BL * ID;   // BL*80
    float* h1   = ssm  + (size_t)BL * 80;   // BL*256 (reused as t1)
    float* h2   = h1   + (size_t)BL * 256;  // BL*256
    float* sbuf = h2   + (size_t)BL * 256;  // BL*4
    float* attn = sbuf + (size_t)BL * 4;    // BL*4
    float* mbuf = attn + (size_t)BL * 4;    // 4*3072
    float* o1   = mbuf + (size_t)BB * RP_ * HD; // 4*256
    float* o2   = o1   + (size_t)BB * 256;  // 4*256

    dim3 blk(256);

    // Input MLP: x(4096,13) -> h1 -> h2 -> h
    gemm_k<<<dim3(256 / BN, BL / BM), blk, 0, stream>>>(
        x, DIN, mlp_in_w1, mlp_in_b1, nullptr, 0, h1, 256, BL, 256, DIN, 1);
    gemm_k<<<dim3(256 / BN, BL / BM), blk, 0, stream>>>(
        h1, 256, mlp_in_w2, mlp_in_b2, nullptr, 0, h2, 256, BL, 256, 256, 1);
    gemm_k<<<dim3(HD / BN, BL / BM), blk, 0, stream>>>(
        h2, 256, mlp_in_w3, mlp_in_b3, nullptr, 0, h, HD, BL, HD, 256, 0);

    for (int l = 0; l < NLAY; ++l) {
        const float* nw  = norm_w     + (size_t)l * HD;
        const float* ipw = in_proj_w  + (size_t)l * 2 * ID * HD;
        const float* cw  = conv_w     + (size_t)l * ID * KD;
        const float* cb  = conv_b     + (size_t)l * ID;
        const float* xpw = x_proj_w   + (size_t)l * 80 * ID;
        const float* dw  = dt_w       + (size_t)l * ID * RD;
        const float* db  = dt_b       + (size_t)l * ID;
        const float* al  = A_log      + (size_t)l * ID * ND;
        const float* dv  = Dp         + (size_t)l * ID;
        const float* opw = out_proj_w + (size_t)l * HD * ID;

        rmsnorm_k<<<BL, blk, 0, stream>>>(h, nw, hn);
        gemm_k<<<dim3(2 * ID / BN, BL / BM), blk, 0, stream>>>(
            hn, HD, ipw, nullptr, nullptr, 0, proj, 2 * ID, BL, 2 * ID, HD, 0);
        conv_silu_k<<<((size_t)BL * ID + 255) / 256, blk, 0, stream>>>(proj, cw, cb, u);
        gemm_k<<<dim3((80 + BN - 1) / BN, BL / BM), blk, 0, stream>>>(
            u, ID, xpw, nullptr, nullptr, 0, ssm, 80, BL, 80, ID, 0);
        gemm_k<<<dim3(ID / BN, BL / BM), blk, 0, stream>>>(
            ssm, 80, dw, db, nullptr, 0, dtb, ID, BL, ID, RD, 3);
        scan_k<<<dim3(ID / 16, BB), blk, 0, stream>>>(dtb, ssm, u, proj, al, dv, yb);
        gemm_k<<<dim3(HD / BN, BL / BM), blk, 0, stream>>>(
            yb, ID, opw, nullptr, h, HD, h, HD, BL, HD, ID, 0);
    }

    // Final norm + attention pooling
    rmsnorm_k<<<BL, blk, 0, stream>>>(h, norm_f_w, hn);
    gemm_k<<<dim3(DA_ / BN, BL / BM), blk, 0, stream>>>(
        hn, HD, attn_ws1, nullptr, nullptr, 0, h1, DA_, BL, DA_, HD, 2);
    gemm_k<<<dim3(1, BL / BM), blk, 0, stream>>>(
        h1, DA_, attn_ws2, nullptr, nullptr, 0, sbuf, RP_, BL, RP_, DA_, 0);
    softmax_k<<<BB * RP_, blk, 0, stream>>>(sbuf, attn);
    pool_k<<<BB * RP_, blk, 0, stream>>>(attn, hn, mbuf);

    // Output MLP: (4,3072) -> 256 -> 256 -> 1
    gemv_k<<<dim3(256, BB), dim3(64), 0, stream>>>(
        mbuf, RP_ * HD, mlp_out_w1, mlp_out_b1, o1, 256, RP_ * HD, 1);
    gemv_k<<<dim3(256, BB), dim3(64), 0, stream>>>(
        o1, 256, mlp_out_w2, mlp_out_b2, o2, 256, 256, 1);
    gemv_k<<<dim3(1, BB), dim3(64), 0, stream>>>(
        o2, 256, mlp_out_w3, mlp_out_b3, out, 1, 256, 0);
}

// Round 2
// 5090.741 us; speedup vs baseline: 2.2588x; 2.2588x over previous
//
#include <hip/hip_runtime.h>
#include <cstddef>
#include <cstdint>

// Model dims
#define HD    768
#define ID    1536
#define ND    16
#define KD    4
#define RD    48
#define NLAY  8
#define BB    4
#define LL    1024
#define BL    4096   // BB*LL
#define DIN   13
#define DA_   128
#define RP_   4

typedef _Float16 f16;
typedef f16 f16x8 __attribute__((ext_vector_type(8)));
typedef float f32x4 __attribute__((ext_vector_type(4)));

__device__ __forceinline__ float softplus_f(float x) {
    return (x > 20.f) ? x : log1pf(expf(x));
}

// ---------------- fp32 -> f16 cast ----------------
__global__ __launch_bounds__(256) void cast_f16_k(
    const float* __restrict__ in, f16* __restrict__ out, int n)
{
    int i = (blockIdx.x * 256 + threadIdx.x) * 4;
    if (i + 3 < n) {
        float4 v = *(const float4*)(in + i);
        out[i]     = (f16)v.x;
        out[i + 1] = (f16)v.y;
        out[i + 2] = (f16)v.z;
        out[i + 3] = (f16)v.w;
    } else {
        for (int j = i; j < n; ++j) out[j] = (f16)in[j];
    }
}

// dt_w (NL*1536 rows of 48) -> padded (rows of 64, zeros at k>=48)
__global__ __launch_bounds__(256) void cast_dtw_k(
    const float* __restrict__ in, f16* __restrict__ out)
{
    int idx = blockIdx.x * 256 + threadIdx.x;   // over NL*1536*64
    if (idx >= NLAY * ID * 64) return;
    int k = idx & 63, r = idx >> 6;
    out[idx] = (k < RD) ? (f16)in[r * RD + k] : (f16)0.f;
}

// ---------------- f16 MFMA GEMM ----------------
// C = act(A @ W^T + bias) (+res). A:(M,K) f16 lda; W:(N,K) f16 ldw.
// C fp32 (optional), Cb f16 copy (optional, cols < ncb).
// Tile 128x128, BK=32, 4 waves. Requires M%128==0, K%32==0, lda/ldw%8==0.
__device__ __forceinline__ void async_copy16(const f16* g, f16* l) {
    __builtin_amdgcn_global_load_lds(
        (const __attribute__((address_space(1))) void*)g,
        (__attribute__((address_space(3))) void*)l, 16, 0, 0);
}

__global__ __launch_bounds__(256) void hgemm_k(
    const f16* __restrict__ A, int lda,
    const f16* __restrict__ W, int ldw,
    const float* __restrict__ bias,
    const float* __restrict__ res, int ldres,
    float* __restrict__ C, int ldc,
    f16* __restrict__ Cb, int ldcb, int ncb,
    int M, int N, int K, int act)
{
    __shared__ f16 As[128 * 32];
    __shared__ f16 Bs[128 * 32];
    int tid = threadIdx.x;
    int wave = tid >> 6, lane = tid & 63;
    int m0 = blockIdx.y * 128, n0 = blockIdx.x * 128;

    int wm = wave & 1, wn = wave >> 1;
    int lm = lane & 15;
    int kq = (lane >> 4) * 8;

    // staging geometry: lane covers (row = chunk16*16 + lane/4, kc = (lane&3)*8)
    int srow = lane >> 2;
    int skc  = (lane & 3) * 8;

    f32x4 acc[4][4] = {};

    for (int k0 = 0; k0 < K; k0 += 32) {
#pragma unroll
        for (int it = 0; it < 2; ++it) {
            int c16 = wave + it * 4;             // 0..7 chunk of 16 rows
            int row = c16 * 16 + srow;
            const f16* ga = A + (size_t)(m0 + row) * lda + k0 + skc;
            const f16* gb = W + (size_t)(n0 + row) * ldw + k0 + skc;
            async_copy16(ga, As + c16 * 512);
            async_copy16(gb, Bs + c16 * 512);
        }
        __syncthreads();

        f16x8 af[4], bf[4];
#pragma unroll
        for (int mt = 0; mt < 4; ++mt)
            af[mt] = *(const f16x8*)(As + (wm * 64 + mt * 16 + lm) * 32 + kq);
#pragma unroll
        for (int nt = 0; nt < 4; ++nt)
            bf[nt] = *(const f16x8*)(Bs + (wn * 64 + nt * 16 + lm) * 32 + kq);
#pragma unroll
        for (int mt = 0; mt < 4; ++mt)
#pragma unroll
            for (int nt = 0; nt < 4; ++nt)
                acc[mt][nt] = __builtin_amdgcn_mfma_f32_16x16x32_f16(
                    af[mt], bf[nt], acc[mt][nt], 0, 0, 0);
        __syncthreads();
    }

    int rq = (lane >> 4) * 4;
#pragma unroll
    for (int mt = 0; mt < 4; ++mt) {
#pragma unroll
        for (int nt = 0; nt < 4; ++nt) {
            int col = n0 + wn * 64 + nt * 16 + lm;
            if (col >= N) continue;
            float bv = bias ? bias[col] : 0.f;
#pragma unroll
            for (int r = 0; r < 4; ++r) {
                int row = m0 + wm * 64 + mt * 16 + rq + r;
                float v = acc[mt][nt][r] + bv;
                if (act == 1) v = fmaxf(v, 0.f);
                else if (act == 2) v = tanhf(v);
                else if (act == 3) v = softplus_f(v);
                if (res) v += res[(size_t)row * ldres + col];
                if (C) C[(size_t)row * ldc + col] = v;
                if (Cb && col < ncb) Cb[(size_t)row * ldcb + col] = (f16)v;
            }
        }
    }
}

// ---------------- fp32 tiled GEMM (small-K cases) ----------------
#define BM 64
#define BN 64
#define BKK 16
__global__ __launch_bounds__(256) void gemm_k(
    const float* __restrict__ A, int lda,
    const float* __restrict__ W,
    const float* __restrict__ bias,
    float* __restrict__ C, int ldc,
    f16* __restrict__ Cb, int ldcb,
    int M, int N, int K, int act)
{
    __shared__ float As[BKK][BM + 4];
    __shared__ float Ws[BKK][BN + 4];
    int tid = threadIdx.x;
    int tx = tid & 15, ty = tid >> 4;
    int m0 = blockIdx.y * BM, n0 = blockIdx.x * BN;
    float acc[4][4] = {};
    int arow = tid >> 2;
    int acol = (tid & 3) * 4;

    for (int k0 = 0; k0 < K; k0 += BKK) {
        int gm = m0 + arow;
        int gn = n0 + arow;
#pragma unroll
        for (int j = 0; j < 4; ++j) {
            int gk = k0 + acol + j;
            float av = 0.f, wv = 0.f;
            if (gm < M && gk < K) av = A[(size_t)gm * lda + gk];
            if (gn < N && gk < K) wv = W[(size_t)gn * K + gk];
            As[acol + j][arow] = av;
            Ws[acol + j][arow] = wv;
        }
        __syncthreads();
#pragma unroll
        for (int k = 0; k < BKK; ++k) {
            float a[4], b[4];
#pragma unroll
            for (int i = 0; i < 4; ++i) a[i] = As[k][ty * 4 + i];
#pragma unroll
            for (int j = 0; j < 4; ++j) b[j] = Ws[k][tx * 4 + j];
#pragma unroll
            for (int i = 0; i < 4; ++i)
#pragma unroll
                for (int j = 0; j < 4; ++j)
                    acc[i][j] += a[i] * b[j];
        }
        __syncthreads();
    }

#pragma unroll
    for (int i = 0; i < 4; ++i) {
        int row = m0 + ty * 4 + i;
        if (row >= M) continue;
#pragma unroll
        for (int j = 0; j < 4; ++j) {
            int col = n0 + tx * 4 + j;
            if (col >= N) continue;
            float v = acc[i][j];
            if (bias) v += bias[col];
            if (act == 1) v = fmaxf(v, 0.f);
            if (C) C[(size_t)row * ldc + col] = v;
            if (Cb) Cb[(size_t)row * ldcb + col] = (f16)v;
        }
    }
}

// ---------------- RMSNorm over 768, f16 out ----------------
__global__ __launch_bounds__(256) void rmsnorm_k(
    const float* __restrict__ x, const float* __restrict__ w,
    f16* __restrict__ out)
{
    int row = blockIdx.x;
    const float* xr = x + (size_t)row * HD;
    int tid = threadIdx.x;
    float v0 = xr[tid], v1 = xr[tid + 256], v2 = xr[tid + 512];
    __shared__ float red[256];
    red[tid] = v0 * v0 + v1 * v1 + v2 * v2;
    __syncthreads();
    for (int o = 128; o; o >>= 1) {
        if (tid < o) red[tid] += red[tid + o];
        __syncthreads();
    }
    float scale = rsqrtf(red[0] / (float)HD + 1e-5f);
    f16* outr = out + (size_t)row * HD;
    outr[tid]       = (f16)(v0 * scale * w[tid]);
    outr[tid + 256] = (f16)(v1 * scale * w[tid + 256]);
    outr[tid + 512] = (f16)(v2 * scale * w[tid + 512]);
}

// ---------------- Causal depthwise conv (K=4) + bias + SiLU ----------------
__global__ __launch_bounds__(256) void conv_silu_k(
    const f16* __restrict__ projb, const float* __restrict__ cw,
    const float* __restrict__ cb, float* __restrict__ u,
    f16* __restrict__ ub)
{
    size_t idx = (size_t)blockIdx.x * 256 + threadIdx.x;
    if (idx >= (size_t)BL * ID) return;
    int i = (int)(idx % ID);
    int t = (int)((idx / ID) % LL);
    int b = (int)(idx / ((size_t)ID * LL));
    float s = cb[i];
#pragma unroll
    for (int k = 0; k < KD; ++k) {
        int tt = t - (KD - 1) + k;
        if (tt >= 0)
            s += (float)projb[((size_t)(b * LL + tt)) * (2 * ID) + i] * cw[i * KD + k];
    }
    float v = s / (1.f + expf(-s));
    u[idx] = v;
    ub[idx] = (f16)v;
}

// ---------------- Selective scan ----------------
__global__ __launch_bounds__(256) void scan_k(
    const float* __restrict__ dt,    // (BL,ID)
    const float* __restrict__ ssm,   // (BL,80): B at +48, C at +64
    const float* __restrict__ u,     // (BL,ID)
    const f16*   __restrict__ projb, // (BL,2*ID): gate at +ID
    const float* __restrict__ A_log, // (ID,ND)
    const float* __restrict__ D,     // (ID)
    f16* __restrict__ y)             // (BL,ID) f16
{
    int b = blockIdx.y;
    int iBase = blockIdx.x * 16;
    int tid = threadIdx.x;
    int n = tid & 15, il = tid >> 4;
    int i = iBase + il;
    float Ain = -expf(A_log[i * ND + n]);
    float Dv = D[i];
    float h = 0.f;
    __shared__ float sdt[64][16], su[64][16], sg[64][16], sB[64][16], sC[64][16];

    for (int t0 = 0; t0 < LL; t0 += 64) {
        __syncthreads();
#pragma unroll
        for (int rr = 0; rr < 4; ++rr) {
            int tt = (tid >> 4) + rr * 16;
            int ii = tid & 15;
            size_t row = (size_t)(b * LL + t0 + tt);
            sdt[tt][ii] = dt[row * ID + iBase + ii];
            su[tt][ii]  = u[row * ID + iBase + ii];
            sg[tt][ii]  = (float)projb[row * (2 * ID) + ID + iBase + ii];
            sB[tt][ii]  = ssm[row * 80 + 48 + ii];
            sC[tt][ii]  = ssm[row * 80 + 64 + ii];
        }
        __syncthreads();
        for (int tt = 0; tt < 64; ++tt) {
            float dtv = sdt[tt][il];
            float uv  = su[tt][il];
            float bv  = sB[tt][n];
            float cv  = sC[tt][n];
            float dA = expf(dtv * Ain);
            h = dA * h + dtv * uv * bv;
            float p = h * cv;
            p += __shfl_xor(p, 1);
            p += __shfl_xor(p, 2);
            p += __shfl_xor(p, 4);
            p += __shfl_xor(p, 8);
            if (n == 0) {
                float g = sg[tt][il];
                float yv = (p + uv * Dv) * (g / (1.f + expf(-g)));
                y[(size_t)(b * LL + t0 + tt) * ID + i] = (f16)yv;
            }
        }
    }
}

// ---------------- Softmax over L per (b,r) ----------------
__global__ __launch_bounds__(256) void softmax_k(
    const float* __restrict__ s, float* __restrict__ attn)
{
    int b = blockIdx.x >> 2, r = blockIdx.x & 3;
    int tid = threadIdx.x;
    __shared__ float red[256];
    float mx = -1e30f;
    for (int j = 0; j < 4; ++j) {
        int t = tid + j * 256;
        mx = fmaxf(mx, s[((size_t)(b * LL + t)) * RP_ + r]);
    }
    red[tid] = mx;
    __syncthreads();
    for (int o = 128; o; o >>= 1) {
        if (tid < o) red[tid] = fmaxf(red[tid], red[tid + o]);
        __syncthreads();
    }
    mx = red[0];
    __syncthreads();
    float ev[4], sum = 0.f;
    for (int j = 0; j < 4; ++j) {
        int t = tid + j * 256;
        ev[j] = expf(s[((size_t)(b * LL + t)) * RP_ + r] - mx);
        sum += ev[j];
    }
    red[tid] = sum;
    __syncthreads();
    for (int o = 128; o; o >>= 1) {
        if (tid < o) red[tid] += red[tid + o];
        __syncthreads();
    }
    float inv = 1.f / red[0];
    for (int j = 0; j < 4; ++j) {
        int t = tid + j * 256;
        attn[((size_t)(b * LL + t)) * RP_ + r] = ev[j] * inv;
    }
}

// ---------------- attn pool ----------------
__global__ __launch_bounds__(256) void pool_k(
    const float* __restrict__ attn, const f16* __restrict__ hn,
    float* __restrict__ m)
{
    int b = blockIdx.x >> 2, r = blockIdx.x & 3;
    int tid = threadIdx.x;
    float acc0 = 0.f, acc1 = 0.f, acc2 = 0.f;
    for (int t = 0; t < LL; ++t) {
        float w = attn[((size_t)(b * LL + t)) * RP_ + r];
        const f16* hr = hn + ((size_t)(b * LL + t)) * HD;
        acc0 += w * (float)hr[tid];
        acc1 += w * (float)hr[tid + 256];
        acc2 += w * (float)hr[tid + 512];
    }
    float* out = m + ((size_t)(b * RP_ + r)) * HD;
    out[tid] = acc0;
    out[tid + 256] = acc1;
    out[tid + 512] = acc2;
}

// ---------------- small GEMV ----------------
__global__ __launch_bounds__(64) void gemv_k(
    const float* __restrict__ A, int lda,
    const float* __restrict__ W, const float* __restrict__ bias,
    float* __restrict__ C, int ldc, int K, int relu)
{
    int n = blockIdx.x, b = blockIdx.y;
    int lane = threadIdx.x;
    const float* a = A + (size_t)b * lda;
    const float* w = W + (size_t)n * K;
    float s = 0.f;
    for (int k = lane; k < K; k += 64) s += a[k] * w[k];
    for (int off = 32; off; off >>= 1) s += __shfl_down(s, off);
    if (lane == 0) {
        float v = s + (bias ? bias[n] : 0.f);
        if (relu) v = fmaxf(v, 0.f);
        C[(size_t)b * ldc + n] = v;
    }
}

extern "C" void kernel_launch(void* const* d_in, const int* in_sizes, int n_in,
                              void* d_out, int out_size, void* d_ws, size_t ws_size,
                              hipStream_t stream) {
    const float* x          = (const float*)d_in[0];
    const float* mlp_in_w1  = (const float*)d_in[1];
    const float* mlp_in_b1  = (const float*)d_in[2];
    const float* mlp_in_w2  = (const float*)d_in[3];
    const float* mlp_in_b2  = (const float*)d_in[4];
    const float* mlp_in_w3  = (const float*)d_in[5];
    const float* mlp_in_b3  = (const float*)d_in[6];
    const float* norm_w     = (const float*)d_in[7];
    const float* in_proj_w  = (const float*)d_in[8];
    const float* conv_w     = (const float*)d_in[9];
    const float* conv_b     = (const float*)d_in[10];
    const float* x_proj_w   = (const float*)d_in[11];
    const float* dt_w       = (const float*)d_in[12];
    const float* dt_b       = (const float*)d_in[13];
    const float* A_log      = (const float*)d_in[14];
    const float* Dp         = (const float*)d_in[15];
    const float* out_proj_w = (const float*)d_in[16];
    const float* norm_f_w   = (const float*)d_in[17];
    const float* attn_ws1   = (const float*)d_in[18];
    const float* attn_ws2   = (const float*)d_in[19];
    const float* mlp_out_w1 = (const float*)d_in[20];
    const float* mlp_out_b1 = (const float*)d_in[21];
    const float* mlp_out_w2 = (const float*)d_in[22];
    const float* mlp_out_b2 = (const float*)d_in[23];
    const float* mlp_out_w3 = (const float*)d_in[24];
    const float* mlp_out_b3 = (const float*)d_in[25];
    float* out = (float*)d_out;

    // ---- workspace layout (fp32 then f16), ~156 MB total ----
    float* ws   = (float*)d_ws;
    float* h    = ws;                        // 4096*768
    float* u    = h    + (size_t)BL * HD;    // 4096*1536
    float* dtb  = u    + (size_t)BL * ID;    // 4096*1536
    float* ssm  = dtb  + (size_t)BL * ID;    // 4096*80
    float* h1a  = ssm  + (size_t)BL * 80;    // 4096*128
    float* sbuf = h1a  + (size_t)BL * DA_;   // 4096*4
    float* attn = sbuf + (size_t)BL * 4;     // 4096*4
    float* mbuf = attn + (size_t)BL * 4;     // 4*3072
    float* o1   = mbuf + (size_t)BB * RP_ * HD;
    float* o2   = o1   + (size_t)BB * 256;
    f16* fb    = (f16*)(o2 + (size_t)BB * 256);
    f16* h1b   = fb;                          // 4096*256
    f16* h2b   = h1b  + (size_t)BL * 256;     // 4096*256
    f16* hnb   = h2b  + (size_t)BL * 256;     // 4096*768
    f16* projb = hnb  + (size_t)BL * HD;      // 4096*3072
    f16* ub    = projb+ (size_t)BL * 2 * ID;  // 4096*1536
    f16* ssmb  = ub   + (size_t)BL * ID;      // 4096*64
    f16* ybb   = ssmb + (size_t)BL * 64;      // 4096*1536
    f16* ipwf  = ybb  + (size_t)BL * ID;      // 3072*768 (per-layer slot)
    f16* opwf  = ipwf + (size_t)2 * ID * HD;  // 8*768*1536
    f16* xpwf  = opwf + (size_t)NLAY * HD * ID; // 8*80*1536
    f16* dwwf  = xpwf + (size_t)NLAY * 80 * ID; // 8*1536*64 (padded)
    f16* w2f   = dwwf + (size_t)NLAY * ID * 64;
    f16* w3f   = w2f  + 256 * 256;
    f16* a1f   = w3f  + HD * 256;

    dim3 blk(256);
    auto cgrid = [](int n) { return dim3((n / 4 + 255) / 256); };

    // ---- weight casts (per call; inputs restored each replay) ----
    cast_f16_k<<<cgrid(256 * 256), blk, 0, stream>>>(mlp_in_w2, w2f, 256 * 256);
    cast_f16_k<<<cgrid(HD * 256), blk, 0, stream>>>(mlp_in_w3, w3f, HD * 256);
    cast_f16_k<<<cgrid(DA_ * HD), blk, 0, stream>>>(attn_ws1, a1f, DA_ * HD);
    cast_f16_k<<<cgrid(NLAY * HD * ID), blk, 0, stream>>>(out_proj_w, opwf, NLAY * HD * ID);
    cast_f16_k<<<cgrid(NLAY * 80 * ID), blk, 0, stream>>>(x_proj_w, xpwf, NLAY * 80 * ID);
    cast_dtw_k<<<(NLAY * ID * 64 + 255) / 256, blk, 0, stream>>>(dt_w, dwwf);

    // ---- input MLP ----
    gemm_k<<<dim3(4, 64), blk, 0, stream>>>(
        x, DIN, mlp_in_w1, mlp_in_b1, nullptr, 0, h1b, 256, BL, 256, DIN, 1);
    hgemm_k<<<dim3(2, 32), blk, 0, stream>>>(
        h1b, 256, w2f, 256, mlp_in_b2, nullptr, 0, nullptr, 0, h2b, 256, 256,
        BL, 256, 256, 1);
    hgemm_k<<<dim3(6, 32), blk, 0, stream>>>(
        h2b, 256, w3f, 256, mlp_in_b3, nullptr, 0, h, HD, nullptr, 0, 0,
        BL, HD, 256, 0);

    for (int l = 0; l < NLAY; ++l) {
        const float* nw  = norm_w + (size_t)l * HD;
        const float* cw  = conv_w + (size_t)l * ID * KD;
        const float* cb  = conv_b + (size_t)l * ID;
        const float* db  = dt_b   + (size_t)l * ID;
        const float* al  = A_log  + (size_t)l * ID * ND;
        const float* dv  = Dp     + (size_t)l * ID;

        cast_f16_k<<<cgrid(2 * ID * HD), blk, 0, stream>>>(
            in_proj_w + (size_t)l * 2 * ID * HD, ipwf, 2 * ID * HD);
        rmsnorm_k<<<BL, blk, 0, stream>>>(h, nw, hnb);
        hgemm_k<<<dim3(24, 32), blk, 0, stream>>>(
            hnb, HD, ipwf, HD, nullptr, nullptr, 0, nullptr, 0,
            projb, 2 * ID, 2 * ID, BL, 2 * ID, HD, 0);
        conv_silu_k<<<(BL * ID) / 256, blk, 0, stream>>>(projb, cw, cb, u, ub);
        hgemm_k<<<dim3(1, 32), blk, 0, stream>>>(
            ub, ID, xpwf + (size_t)l * 80 * ID, ID, nullptr, nullptr, 0,
            ssm, 80, ssmb, 64, RD, BL, 80, ID, 0);
        hgemm_k<<<dim3(12, 32), blk, 0, stream>>>(
            ssmb, 64, dwwf + (size_t)l * ID * 64, 64, db, nullptr, 0,
            dtb, ID, nullptr, 0, 0, BL, ID, 64, 3);
        scan_k<<<dim3(ID / 16, BB), blk, 0, stream>>>(dtb, ssm, u, projb, al, dv, ybb);
        hgemm_k<<<dim3(6, 32), blk, 0, stream>>>(
            ybb, ID, opwf + (size_t)l * HD * ID, ID, nullptr, h, HD,
            h, HD, nullptr, 0, 0, BL, HD, ID, 0);
    }

    // ---- final norm + attention pooling ----
    rmsnorm_k<<<BL, blk, 0, stream>>>(h, norm_f_w, hnb);
    hgemm_k<<<dim3(1, 32), blk, 0, stream>>>(
        hnb, HD, a1f, HD, nullptr, nullptr, 0, h1a, DA_, nullptr, 0, 0,
        BL, DA_, HD, 2);
    gemm_k<<<dim3(1, 64), blk, 0, stream>>>(
        h1a, DA_, attn_ws2, nullptr, sbuf, RP_, nullptr, 0, BL, RP_, DA_, 0);
    softmax_k<<<BB * RP_, blk, 0, stream>>>(sbuf, attn);
    pool_k<<<BB * RP_, blk, 0, stream>>>(attn, hnb, mbuf);

    // ---- output MLP ----
    gemv_k<<<dim3(256, BB), dim3(64), 0, stream>>>(
        mbuf, RP_ * HD, mlp_out_w1, mlp_out_b1, o1, 256, RP_ * HD, 1);
    gemv_k<<<dim3(256, BB), dim3(64), 0, stream>>>(
        o1, 256, mlp_out_w2, mlp_out_b2, o2, 256, 256, 1);
    gemv_k<<<dim3(1, BB), dim3(64), 0, stream>>>(
        o2, 256, mlp_out_w3, mlp_out_b3, out, 1, 256, 0);
}

// Round 3
// 2877.161 us; speedup vs baseline: 3.9966x; 1.7694x over previous
//
#include <hip/hip_runtime.h>
#include <cstddef>
#include <cstdint>

// Model dims
#define HD    768
#define ID    1536
#define ND    16
#define KD    4
#define RD    48
#define NLAY  8
#define BB    4
#define LL    1024
#define BL    4096   // BB*LL
#define DIN   13
#define DA_   128
#define RP_   4

// scan chunking
#define NC    32
#define CS    32     // LL/NC

typedef _Float16 f16;
typedef f16 f16x8 __attribute__((ext_vector_type(8)));
typedef float f32x4 __attribute__((ext_vector_type(4)));

__device__ __forceinline__ float softplus_f(float x) {
    return (x > 20.f) ? x : log1pf(expf(x));
}

__device__ __forceinline__ float fast_exp2(float x) {
#if __has_builtin(__builtin_amdgcn_exp2f)
    return __builtin_amdgcn_exp2f(x);
#else
    return exp2f(x);
#endif
}

// ---------------- fp32 -> f16 cast ----------------
__global__ __launch_bounds__(256) void cast_f16_k(
    const float* __restrict__ in, f16* __restrict__ out, int n)
{
    int i = (blockIdx.x * 256 + threadIdx.x) * 4;
    if (i + 3 < n) {
        float4 v = *(const float4*)(in + i);
        out[i]     = (f16)v.x;
        out[i + 1] = (f16)v.y;
        out[i + 2] = (f16)v.z;
        out[i + 3] = (f16)v.w;
    } else {
        for (int j = i; j < n; ++j) out[j] = (f16)in[j];
    }
}

// dt_w (NL*1536 rows of 48) -> padded (rows of 64, zeros at k>=48)
__global__ __launch_bounds__(256) void cast_dtw_k(
    const float* __restrict__ in, f16* __restrict__ out)
{
    int idx = blockIdx.x * 256 + threadIdx.x;
    if (idx >= NLAY * ID * 64) return;
    int k = idx & 63, r = idx >> 6;
    out[idx] = (k < RD) ? (f16)in[r * RD + k] : (f16)0.f;
}

// ---------------- f16 MFMA GEMM ----------------
__device__ __forceinline__ void async_copy16(const f16* g, f16* l) {
    __builtin_amdgcn_global_load_lds(
        (const __attribute__((address_space(1))) void*)g,
        (__attribute__((address_space(3))) void*)l, 16, 0, 0);
}

__global__ __launch_bounds__(256) void hgemm_k(
    const f16* __restrict__ A, int lda,
    const f16* __restrict__ W, int ldw,
    const float* __restrict__ bias,
    const float* __restrict__ res, int ldres,
    float* __restrict__ C, int ldc,
    f16* __restrict__ Cb, int ldcb, int ncb,
    int M, int N, int K, int act)
{
    __shared__ f16 As[128 * 32];
    __shared__ f16 Bs[128 * 32];
    int tid = threadIdx.x;
    int wave = tid >> 6, lane = tid & 63;
    int m0 = blockIdx.y * 128, n0 = blockIdx.x * 128;

    int wm = wave & 1, wn = wave >> 1;
    int lm = lane & 15;
    int kq = (lane >> 4) * 8;

    int srow = lane >> 2;
    int skc  = (lane & 3) * 8;

    f32x4 acc[4][4] = {};

    for (int k0 = 0; k0 < K; k0 += 32) {
#pragma unroll
        for (int it = 0; it < 2; ++it) {
            int c16 = wave + it * 4;
            int row = c16 * 16 + srow;
            const f16* ga = A + (size_t)(m0 + row) * lda + k0 + skc;
            const f16* gb = W + (size_t)(n0 + row) * ldw + k0 + skc;
            async_copy16(ga, As + c16 * 512);
            async_copy16(gb, Bs + c16 * 512);
        }
        __syncthreads();

        f16x8 af[4], bf[4];
#pragma unroll
        for (int mt = 0; mt < 4; ++mt)
            af[mt] = *(const f16x8*)(As + (wm * 64 + mt * 16 + lm) * 32 + kq);
#pragma unroll
        for (int nt = 0; nt < 4; ++nt)
            bf[nt] = *(const f16x8*)(Bs + (wn * 64 + nt * 16 + lm) * 32 + kq);
#pragma unroll
        for (int mt = 0; mt < 4; ++mt)
#pragma unroll
            for (int nt = 0; nt < 4; ++nt)
                acc[mt][nt] = __builtin_amdgcn_mfma_f32_16x16x32_f16(
                    af[mt], bf[nt], acc[mt][nt], 0, 0, 0);
        __syncthreads();
    }

    int rq = (lane >> 4) * 4;
#pragma unroll
    for (int mt = 0; mt < 4; ++mt) {
#pragma unroll
        for (int nt = 0; nt < 4; ++nt) {
            int col = n0 + wn * 64 + nt * 16 + lm;
            if (col >= N) continue;
            float bv = bias ? bias[col] : 0.f;
#pragma unroll
            for (int r = 0; r < 4; ++r) {
                int row = m0 + wm * 64 + mt * 16 + rq + r;
                float v = acc[mt][nt][r] + bv;
                if (act == 1) v = fmaxf(v, 0.f);
                else if (act == 2) v = tanhf(v);
                else if (act == 3) v = softplus_f(v);
                if (res) v += res[(size_t)row * ldres + col];
                if (C) C[(size_t)row * ldc + col] = v;
                if (Cb && col < ncb) Cb[(size_t)row * ldcb + col] = (f16)v;
            }
        }
    }
}

// ---------------- fp32 tiled GEMM (small-K cases) ----------------
#define BM 64
#define BN 64
#define BKK 16
__global__ __launch_bounds__(256) void gemm_k(
    const float* __restrict__ A, int lda,
    const float* __restrict__ W,
    const float* __restrict__ bias,
    float* __restrict__ C, int ldc,
    f16* __restrict__ Cb, int ldcb,
    int M, int N, int K, int act)
{
    __shared__ float As[BKK][BM + 4];
    __shared__ float Ws[BKK][BN + 4];
    int tid = threadIdx.x;
    int tx = tid & 15, ty = tid >> 4;
    int m0 = blockIdx.y * BM, n0 = blockIdx.x * BN;
    float acc[4][4] = {};
    int arow = tid >> 2;
    int acol = (tid & 3) * 4;

    for (int k0 = 0; k0 < K; k0 += BKK) {
        int gm = m0 + arow;
        int gn = n0 + arow;
#pragma unroll
        for (int j = 0; j < 4; ++j) {
            int gk = k0 + acol + j;
            float av = 0.f, wv = 0.f;
            if (gm < M && gk < K) av = A[(size_t)gm * lda + gk];
            if (gn < N && gk < K) wv = W[(size_t)gn * K + gk];
            As[acol + j][arow] = av;
            Ws[acol + j][arow] = wv;
        }
        __syncthreads();
#pragma unroll
        for (int k = 0; k < BKK; ++k) {
            float a[4], b[4];
#pragma unroll
            for (int i = 0; i < 4; ++i) a[i] = As[k][ty * 4 + i];
#pragma unroll
            for (int j = 0; j < 4; ++j) b[j] = Ws[k][tx * 4 + j];
#pragma unroll
            for (int i = 0; i < 4; ++i)
#pragma unroll
                for (int j = 0; j < 4; ++j)
                    acc[i][j] += a[i] * b[j];
        }
        __syncthreads();
    }

#pragma unroll
    for (int i = 0; i < 4; ++i) {
        int row = m0 + ty * 4 + i;
        if (row >= M) continue;
#pragma unroll
        for (int j = 0; j < 4; ++j) {
            int col = n0 + tx * 4 + j;
            if (col >= N) continue;
            float v = acc[i][j];
            if (bias) v += bias[col];
            if (act == 1) v = fmaxf(v, 0.f);
            if (C) C[(size_t)row * ldc + col] = v;
            if (Cb) Cb[(size_t)row * ldcb + col] = (f16)v;
        }
    }
}

// ---------------- RMSNorm over 768, f16 out ----------------
__global__ __launch_bounds__(256) void rmsnorm_k(
    const float* __restrict__ x, const float* __restrict__ w,
    f16* __restrict__ out)
{
    int row = blockIdx.x;
    const float* xr = x + (size_t)row * HD;
    int tid = threadIdx.x;
    float v0 = xr[tid], v1 = xr[tid + 256], v2 = xr[tid + 512];
    __shared__ float red[256];
    red[tid] = v0 * v0 + v1 * v1 + v2 * v2;
    __syncthreads();
    for (int o = 128; o; o >>= 1) {
        if (tid < o) red[tid] += red[tid + o];
        __syncthreads();
    }
    float scale = rsqrtf(red[0] / (float)HD + 1e-5f);
    f16* outr = out + (size_t)row * HD;
    outr[tid]       = (f16)(v0 * scale * w[tid]);
    outr[tid + 256] = (f16)(v1 * scale * w[tid + 256]);
    outr[tid + 512] = (f16)(v2 * scale * w[tid + 512]);
}

// ---------------- Causal depthwise conv (K=4) + bias + SiLU ----------------
__global__ __launch_bounds__(256) void conv_silu_k(
    const f16* __restrict__ projb, const float* __restrict__ cw,
    const float* __restrict__ cb, f16* __restrict__ ub)
{
    size_t idx = (size_t)blockIdx.x * 256 + threadIdx.x;
    if (idx >= (size_t)BL * ID) return;
    int i = (int)(idx % ID);
    int t = (int)((idx / ID) % LL);
    int b = (int)(idx / ((size_t)ID * LL));
    float s = cb[i];
#pragma unroll
    for (int k = 0; k < KD; ++k) {
        int tt = t - (KD - 1) + k;
        if (tt >= 0)
            s += (float)projb[((size_t)(b * LL + tt)) * (2 * ID) + i] * cw[i * KD + k];
    }
    float v = s / (1.f + expf(-s));
    ub[idx] = (f16)v;
}

// ---------------- Selective scan: chunked two-pass ----------------
// Pass 1: per (b, chunk, channel) lane; 16 states in regs from h=0;
// writes P[n] = prod dA, H[n] = chunk-local scan result.
__global__ __launch_bounds__(256) void scan1_k(
    const float* __restrict__ dtb,   // (BL,ID)
    const float* __restrict__ ssm,   // (BL,80): B at +48
    const f16*   __restrict__ ub,    // (BL,ID)
    const float* __restrict__ A_log, // (ID,16)
    float* __restrict__ Pw, float* __restrict__ Hw)
{
    int b = blockIdx.z, c = blockIdx.y;
    int i = blockIdx.x * 256 + threadIdx.x;
    __shared__ float sB[CS * 16];
    for (int idx = threadIdx.x; idx < CS * 16; idx += 256) {
        int t = idx >> 4, n = idx & 15;
        sB[idx] = ssm[((size_t)(b * LL + c * CS + t)) * 80 + 48 + n];
    }
    __syncthreads();

    float Ain[16];
#pragma unroll
    for (int n = 0; n < 16; ++n)
        Ain[n] = -expf(A_log[i * ND + n]) * 1.44269504f;  // fold log2(e)

    float h[16], P[16];
#pragma unroll
    for (int n = 0; n < 16; ++n) { h[n] = 0.f; P[n] = 1.f; }

    for (int t = 0; t < CS; ++t) {
        size_t row = (size_t)(b * LL + c * CS + t);
        float dtv = dtb[row * ID + i];
        float x = dtv * (float)ub[row * ID + i];
        const float4* Bv = (const float4*)(sB + t * 16);
        float4 B0 = Bv[0], B1 = Bv[1], B2 = Bv[2], B3 = Bv[3];
        float Bf[16] = {B0.x, B0.y, B0.z, B0.w, B1.x, B1.y, B1.z, B1.w,
                        B2.x, B2.y, B2.z, B2.w, B3.x, B3.y, B3.z, B3.w};
#pragma unroll
        for (int n = 0; n < 16; ++n) {
            float dA = fast_exp2(dtv * Ain[n]);
            h[n] = dA * h[n] + x * Bf[n];
            P[n] *= dA;
        }
    }
    size_t off = (((size_t)(b * NC + c) * ID + i) << 4);
    float4* pw = (float4*)(Pw + off);
    float4* hw = (float4*)(Hw + off);
#pragma unroll
    for (int q = 0; q < 4; ++q) {
        pw[q] = make_float4(P[q*4], P[q*4+1], P[q*4+2], P[q*4+3]);
        hw[q] = make_float4(h[q*4], h[q*4+1], h[q*4+2], h[q*4+3]);
    }
}

// Combine: per (b,i,n) serial over chunks; rewrites Hw[c] with the ENTRY
// state of chunk c (in place).
__global__ __launch_bounds__(256) void scan_comb_k(
    const float* __restrict__ Pw, float* __restrict__ Hw)
{
    int idx = blockIdx.x * 256 + threadIdx.x;   // over BB*ID*16
    int rem = idx & (ID * 16 - 1);
    int b = idx / (ID * 16);
    size_t base = (size_t)b * NC * ID * 16 + rem;
    float e = 0.f;
    for (int c = 0; c < NC; ++c) {
        size_t off = base + (size_t)c * ID * 16;
        float Hc = Hw[off];
        float Pc = Pw[off];
        Hw[off] = e;
        e = Hc + Pc * e;
    }
}

// Pass 2: re-scan each chunk from its entry state, emit y (D-skip + gate SiLU).
__global__ __launch_bounds__(256) void scan2_k(
    const float* __restrict__ dtb,
    const float* __restrict__ ssm,   // B at +48, C at +64
    const f16*   __restrict__ ub,
    const f16*   __restrict__ projb, // gate at +ID
    const float* __restrict__ A_log,
    const float* __restrict__ D,
    const float* __restrict__ Hw,    // entry states
    f16* __restrict__ y)
{
    int b = blockIdx.z, c = blockIdx.y;
    int i = blockIdx.x * 256 + threadIdx.x;
    __shared__ float sB[CS * 16];
    __shared__ float sC[CS * 16];
    for (int idx = threadIdx.x; idx < CS * 16; idx += 256) {
        int t = idx >> 4, n = idx & 15;
        size_t row = (size_t)(b * LL + c * CS + t);
        sB[idx] = ssm[row * 80 + 48 + n];
        sC[idx] = ssm[row * 80 + 64 + n];
    }
    __syncthreads();

    float Ain[16];
#pragma unroll
    for (int n = 0; n < 16; ++n)
        Ain[n] = -expf(A_log[i * ND + n]) * 1.44269504f;
    float Dv = D[i];

    float h[16];
    size_t off = (((size_t)(b * NC + c) * ID + i) << 4);
    const float4* hw = (const float4*)(Hw + off);
#pragma unroll
    for (int q = 0; q < 4; ++q) {
        float4 v = hw[q];
        h[q*4] = v.x; h[q*4+1] = v.y; h[q*4+2] = v.z; h[q*4+3] = v.w;
    }

    for (int t = 0; t < CS; ++t) {
        size_t row = (size_t)(b * LL + c * CS + t);
        float dtv = dtb[row * ID + i];
        float uv  = (float)ub[row * ID + i];
        float g   = (float)projb[row * (2 * ID) + ID + i];
        float x = dtv * uv;
        const float4* Bv = (const float4*)(sB + t * 16);
        const float4* Cv = (const float4*)(sC + t * 16);
        float4 B0 = Bv[0], B1 = Bv[1], B2 = Bv[2], B3 = Bv[3];
        float4 C0 = Cv[0], C1 = Cv[1], C2 = Cv[2], C3 = Cv[3];
        float Bf[16] = {B0.x, B0.y, B0.z, B0.w, B1.x, B1.y, B1.z, B1.w,
                        B2.x, B2.y, B2.z, B2.w, B3.x, B3.y, B3.z, B3.w};
        float Cf[16] = {C0.x, C0.y, C0.z, C0.w, C1.x, C1.y, C1.z, C1.w,
                        C2.x, C2.y, C2.z, C2.w, C3.x, C3.y, C3.z, C3.w};
        float yv = 0.f;
#pragma unroll
        for (int n = 0; n < 16; ++n) {
            float dA = fast_exp2(dtv * Ain[n]);
            h[n] = dA * h[n] + x * Bf[n];
            yv += h[n] * Cf[n];
        }
        yv = (yv + uv * Dv) * (g / (1.f + expf(-g)));
        y[row * ID + i] = (f16)yv;
    }
}

// ---------------- Softmax over L per (b,r) ----------------
__global__ __launch_bounds__(256) void softmax_k(
    const float* __restrict__ s, float* __restrict__ attn)
{
    int b = blockIdx.x >> 2, r = blockIdx.x & 3;
    int tid = threadIdx.x;
    __shared__ float red[256];
    float mx = -1e30f;
    for (int j = 0; j < 4; ++j) {
        int t = tid + j * 256;
        mx = fmaxf(mx, s[((size_t)(b * LL + t)) * RP_ + r]);
    }
    red[tid] = mx;
    __syncthreads();
    for (int o = 128; o; o >>= 1) {
        if (tid < o) red[tid] = fmaxf(red[tid], red[tid + o]);
        __syncthreads();
    }
    mx = red[0];
    __syncthreads();
    float ev[4], sum = 0.f;
    for (int j = 0; j < 4; ++j) {
        int t = tid + j * 256;
        ev[j] = expf(s[((size_t)(b * LL + t)) * RP_ + r] - mx);
        sum += ev[j];
    }
    red[tid] = sum;
    __syncthreads();
    for (int o = 128; o; o >>= 1) {
        if (tid < o) red[tid] += red[tid + o];
        __syncthreads();
    }
    float inv = 1.f / red[0];
    for (int j = 0; j < 4; ++j) {
        int t = tid + j * 256;
        attn[((size_t)(b * LL + t)) * RP_ + r] = ev[j] * inv;
    }
}

// ---------------- attn pool ----------------
__global__ __launch_bounds__(256) void pool_k(
    const float* __restrict__ attn, const f16* __restrict__ hn,
    float* __restrict__ m)
{
    int b = blockIdx.x >> 2, r = blockIdx.x & 3;
    int tid = threadIdx.x;
    float acc0 = 0.f, acc1 = 0.f, acc2 = 0.f;
    for (int t = 0; t < LL; ++t) {
        float w = attn[((size_t)(b * LL + t)) * RP_ + r];
        const f16* hr = hn + ((size_t)(b * LL + t)) * HD;
        acc0 += w * (float)hr[tid];
        acc1 += w * (float)hr[tid + 256];
        acc2 += w * (float)hr[tid + 512];
    }
    float* out = m + ((size_t)(b * RP_ + r)) * HD;
    out[tid] = acc0;
    out[tid + 256] = acc1;
    out[tid + 512] = acc2;
}

// ---------------- small GEMV ----------------
__global__ __launch_bounds__(64) void gemv_k(
    const float* __restrict__ A, int lda,
    const float* __restrict__ W, const float* __restrict__ bias,
    float* __restrict__ C, int ldc, int K, int relu)
{
    int n = blockIdx.x, b = blockIdx.y;
    int lane = threadIdx.x;
    const float* a = A + (size_t)b * lda;
    const float* w = W + (size_t)n * K;
    float s = 0.f;
    for (int k = lane; k < K; k += 64) s += a[k] * w[k];
    for (int off = 32; off; off >>= 1) s += __shfl_down(s, off);
    if (lane == 0) {
        float v = s + (bias ? bias[n] : 0.f);
        if (relu) v = fmaxf(v, 0.f);
        C[(size_t)b * ldc + n] = v;
    }
}

extern "C" void kernel_launch(void* const* d_in, const int* in_sizes, int n_in,
                              void* d_out, int out_size, void* d_ws, size_t ws_size,
                              hipStream_t stream) {
    const float* x          = (const float*)d_in[0];
    const float* mlp_in_w1  = (const float*)d_in[1];
    const float* mlp_in_b1  = (const float*)d_in[2];
    const float* mlp_in_w2  = (const float*)d_in[3];
    const float* mlp_in_b2  = (const float*)d_in[4];
    const float* mlp_in_w3  = (const float*)d_in[5];
    const float* mlp_in_b3  = (const float*)d_in[6];
    const float* norm_w     = (const float*)d_in[7];
    const float* in_proj_w  = (const float*)d_in[8];
    const float* conv_w     = (const float*)d_in[9];
    const float* conv_b     = (const float*)d_in[10];
    const float* x_proj_w   = (const float*)d_in[11];
    const float* dt_w       = (const float*)d_in[12];
    const float* dt_b       = (const float*)d_in[13];
    const float* A_log      = (const float*)d_in[14];
    const float* Dp         = (const float*)d_in[15];
    const float* out_proj_w = (const float*)d_in[16];
    const float* norm_f_w   = (const float*)d_in[17];
    const float* attn_ws1   = (const float*)d_in[18];
    const float* attn_ws2   = (const float*)d_in[19];
    const float* mlp_out_w1 = (const float*)d_in[20];
    const float* mlp_out_b1 = (const float*)d_in[21];
    const float* mlp_out_w2 = (const float*)d_in[22];
    const float* mlp_out_b2 = (const float*)d_in[23];
    const float* mlp_out_w3 = (const float*)d_in[24];
    const float* mlp_out_b3 = (const float*)d_in[25];
    float* out = (float*)d_out;

    // ---- workspace layout (~156 MB; Round-1's 161 MB layout worked) ----
    float* ws   = (float*)d_ws;
    float* h    = ws;                        // 4096*768
    float* dtb  = h    + (size_t)BL * HD;    // 4096*1536
    float* ssm  = dtb  + (size_t)BL * ID;    // 4096*80
    float* h1a  = ssm  + (size_t)BL * 80;    // 4096*128
    float* sbuf = h1a  + (size_t)BL * DA_;   // 4096*4
    float* attn = sbuf + (size_t)BL * 4;     // 4096*4
    float* mbuf = attn + (size_t)BL * 4;     // 4*3072
    float* o1   = mbuf + (size_t)BB * RP_ * HD;
    float* o2   = o1   + (size_t)BB * 256;
    float* Pw   = o2   + (size_t)BB * 256;   // 4*32*1536*16
    float* Hw   = Pw   + (size_t)BB * NC * ID * 16;
    f16* fb    = (f16*)(Hw + (size_t)BB * NC * ID * 16);
    f16* h1b   = fb;                          // 4096*256
    f16* h2b   = h1b  + (size_t)BL * 256;     // 4096*256
    f16* hnb   = h2b  + (size_t)BL * 256;     // 4096*768
    f16* projb = hnb  + (size_t)BL * HD;      // 4096*3072
    f16* ub    = projb+ (size_t)BL * 2 * ID;  // 4096*1536
    f16* ssmb  = ub   + (size_t)BL * ID;      // 4096*64
    f16* ybb   = ssmb + (size_t)BL * 64;      // 4096*1536
    f16* ipwf  = ybb  + (size_t)BL * ID;      // 3072*768 (per-layer slot)
    f16* opwf  = ipwf + (size_t)2 * ID * HD;  // 8*768*1536
    f16* xpwf  = opwf + (size_t)NLAY * HD * ID;
    f16* dwwf  = xpwf + (size_t)NLAY * 80 * ID;
    f16* w2f   = dwwf + (size_t)NLAY * ID * 64;
    f16* w3f   = w2f  + 256 * 256;
    f16* a1f   = w3f  + HD * 256;

    dim3 blk(256);
    auto cgrid = [](int n) { return dim3((n / 4 + 255) / 256); };

    // ---- weight casts ----
    cast_f16_k<<<cgrid(256 * 256), blk, 0, stream>>>(mlp_in_w2, w2f, 256 * 256);
    cast_f16_k<<<cgrid(HD * 256), blk, 0, stream>>>(mlp_in_w3, w3f, HD * 256);
    cast_f16_k<<<cgrid(DA_ * HD), blk, 0, stream>>>(attn_ws1, a1f, DA_ * HD);
    cast_f16_k<<<cgrid(NLAY * HD * ID), blk, 0, stream>>>(out_proj_w, opwf, NLAY * HD * ID);
    cast_f16_k<<<cgrid(NLAY * 80 * ID), blk, 0, stream>>>(x_proj_w, xpwf, NLAY * 80 * ID);
    cast_dtw_k<<<(NLAY * ID * 64 + 255) / 256, blk, 0, stream>>>(dt_w, dwwf);

    // ---- input MLP ----
    gemm_k<<<dim3(4, 64), blk, 0, stream>>>(
        x, DIN, mlp_in_w1, mlp_in_b1, nullptr, 0, h1b, 256, BL, 256, DIN, 1);
    hgemm_k<<<dim3(2, 32), blk, 0, stream>>>(
        h1b, 256, w2f, 256, mlp_in_b2, nullptr, 0, nullptr, 0, h2b, 256, 256,
        BL, 256, 256, 1);
    hgemm_k<<<dim3(6, 32), blk, 0, stream>>>(
        h2b, 256, w3f, 256, mlp_in_b3, nullptr, 0, h, HD, nullptr, 0, 0,
        BL, HD, 256, 0);

    for (int l = 0; l < NLAY; ++l) {
        const float* nw  = norm_w + (size_t)l * HD;
        const float* cw  = conv_w + (size_t)l * ID * KD;
        const float* cb  = conv_b + (size_t)l * ID;
        const float* db  = dt_b   + (size_t)l * ID;
        const float* al  = A_log  + (size_t)l * ID * ND;
        const float* dv  = Dp     + (size_t)l * ID;

        cast_f16_k<<<cgrid(2 * ID * HD), blk, 0, stream>>>(
            in_proj_w + (size_t)l * 2 * ID * HD, ipwf, 2 * ID * HD);
        rmsnorm_k<<<BL, blk, 0, stream>>>(h, nw, hnb);
        hgemm_k<<<dim3(24, 32), blk, 0, stream>>>(
            hnb, HD, ipwf, HD, nullptr, nullptr, 0, nullptr, 0,
            projb, 2 * ID, 2 * ID, BL, 2 * ID, HD, 0);
        conv_silu_k<<<(BL * ID) / 256, blk, 0, stream>>>(projb, cw, cb, ub);
        hgemm_k<<<dim3(1, 32), blk, 0, stream>>>(
            ub, ID, xpwf + (size_t)l * 80 * ID, ID, nullptr, nullptr, 0,
            ssm, 80, ssmb, 64, RD, BL, 80, ID, 0);
        hgemm_k<<<dim3(12, 32), blk, 0, stream>>>(
            ssmb, 64, dwwf + (size_t)l * ID * 64, 64, db, nullptr, 0,
            dtb, ID, nullptr, 0, 0, BL, ID, 64, 3);

        scan1_k<<<dim3(ID / 256, NC, BB), blk, 0, stream>>>(
            dtb, ssm, ub, al, Pw, Hw);
        scan_comb_k<<<(BB * ID * 16) / 256, blk, 0, stream>>>(Pw, Hw);
        scan2_k<<<dim3(ID / 256, NC, BB), blk, 0, stream>>>(
            dtb, ssm, ub, projb, al, dv, Hw, ybb);

        hgemm_k<<<dim3(6, 32), blk, 0, stream>>>(
            ybb, ID, opwf + (size_t)l * HD * ID, ID, nullptr, h, HD,
            h, HD, nullptr, 0, 0, BL, HD, ID, 0);
    }

    // ---- final norm + attention pooling ----
    rmsnorm_k<<<BL, blk, 0, stream>>>(h, norm_f_w, hnb);
    hgemm_k<<<dim3(1, 32), blk, 0, stream>>>(
        hnb, HD, a1f, HD, nullptr, nullptr, 0, h1a, DA_, nullptr, 0, 0,
        BL, DA_, HD, 2);
    gemm_k<<<dim3(1, 64), blk, 0, stream>>>(
        h1a, DA_, attn_ws2, nullptr, sbuf, RP_, nullptr, 0, BL, RP_, DA_, 0);
    softmax_k<<<BB * RP_, blk, 0, stream>>>(sbuf, attn);
    pool_k<<<BB * RP_, blk, 0, stream>>>(attn, hnb, mbuf);

    // ---- output MLP ----
    gemv_k<<<dim3(256, BB), dim3(64), 0, stream>>>(
        mbuf, RP_ * HD, mlp_out_w1, mlp_out_b1, o1, 256, RP_ * HD, 1);
    gemv_k<<<dim3(256, BB), dim3(64), 0, stream>>>(
        o1, 256, mlp_out_w2, mlp_out_b2, o2, 256, 256, 1);
    gemv_k<<<dim3(1, BB), dim3(64), 0, stream>>>(
        o2, 256, mlp_out_w3, mlp_out_b3, out, 1, 256, 0);
}